// Round 5
// baseline (11078.245 us; speedup 1.0000x reference)
//
#include <hip/hip_runtime.h>
#include <hip/hip_bf16.h>
#include <math.h>

// LSTM decoder: B=64, T=512, IN=256, OUT=256, H=1024, 2 layers + linear head.
// Round 5: persistent kernel (256 blocks x 512 threads), weights in VGPRs,
// cell state in registers, single grid barrier per step, write-through h
// stores + cached h loads with acquire-inv coherence. Change vs R4: the
// buffer_inv of ALL blocks now fires in a tight cluster right at barrier
// release (proj moved AFTER bar_wait), so per-XCD L2 fills survive the
// interval and the 106 MB/step A-broadcast is served by L2 (36.9 TB/s)
// instead of the LLC (~6 TB/s, the R3/R4 bottleneck). s_sleep(1) shrinks
// poll skew.

typedef __attribute__((ext_vector_type(8))) short bf16x8;   // 8 x bf16
typedef __attribute__((ext_vector_type(4))) float f32x4;

__device__ __forceinline__ float sigm(float v) { return 1.f / (1.f + expf(-v)); }

// write-through (sc0 sc1) 2B store for h publication
__device__ __forceinline__ void vstore_bf16(__hip_bfloat16* p, float v) {
  __hip_bfloat16 hb = __float2bfloat16(v);
  unsigned short us;
  __builtin_memcpy(&us, &hb, 2);
  *(volatile unsigned short*)p = us;
}

// ---------------- prep kernels (one-time per launch) ----------------

// W0cat[u*4+g][k] : k<256 -> Wih0[g*1024+u][k], else Whh0[g*1024+u][k-256]
__global__ __launch_bounds__(256) void prep_w0(const float* __restrict__ Wih0,
                                               const float* __restrict__ Whh0,
                                               __hip_bfloat16* __restrict__ W0) {
  const unsigned n = 4096u * 1280u;
  for (unsigned d = blockIdx.x * blockDim.x + threadIdx.x; d < n;
       d += blockDim.x * gridDim.x) {
    unsigned r = d / 1280u;
    unsigned k = d - r * 1280u;
    unsigned u = r >> 2, g = r & 3u;
    unsigned srow = g * 1024u + u;
    float v = (k < 256u) ? Wih0[(size_t)srow * 256u + k]
                         : Whh0[(size_t)srow * 1024u + (k - 256u)];
    W0[d] = __float2bfloat16(v);
  }
}

// W1ext[4352][2048]: rows<4096 reordered LSTM1 weights [Wih1|Whh1];
// rows 4096+o: [zeros(1024) | Wlin[o]]
__global__ __launch_bounds__(256) void prep_w1(const float* __restrict__ Wih1,
                                               const float* __restrict__ Whh1,
                                               const float* __restrict__ Wlin,
                                               __hip_bfloat16* __restrict__ W1) {
  const unsigned n = 4352u * 2048u;
  for (unsigned d = blockIdx.x * blockDim.x + threadIdx.x; d < n;
       d += blockDim.x * gridDim.x) {
    unsigned r = d >> 11;
    unsigned k = d & 2047u;
    float v;
    if (r < 4096u) {
      unsigned u = r >> 2, g = r & 3u;
      unsigned srow = g * 1024u + u;
      v = (k < 1024u) ? Wih1[(size_t)srow * 1024u + k]
                      : Whh1[(size_t)srow * 1024u + (k - 1024u)];
    } else {
      unsigned o = r - 4096u;
      v = (k < 1024u) ? 0.f : Wlin[(size_t)o * 1024u + (k - 1024u)];
    }
    W1[d] = __float2bfloat16(v);
  }
}

// xbf[t][b][k] = bf16( t==0 ? 0 : x[b][t-1][k] )   (teacher forcing shift)
__global__ __launch_bounds__(256) void prep_x(const float* __restrict__ x,
                                              __hip_bfloat16* __restrict__ xbf) {
  const unsigned n = 512u * 64u * 256u;
  for (unsigned d = blockIdx.x * blockDim.x + threadIdx.x; d < n;
       d += blockDim.x * gridDim.x) {
    unsigned t = d >> 14;
    unsigned b = (d >> 8) & 63u;
    unsigned k = d & 255u;
    float v = (t == 0u) ? 0.f : x[((size_t)b * 512u + (t - 1u)) * 256u + k];
    xbf[d] = __float2bfloat16(v);
  }
}

// biases (gate-interleaved, bih+bhh combined) + h init: h0[-1] -> slot 0,
// h1[-1] -> slot 2 (h1 triple-buffered, B_0 reads slot (0+2)%3 = 2)
__global__ __launch_bounds__(256) void prep_misc(
    const float* __restrict__ bih0, const float* __restrict__ bhh0,
    const float* __restrict__ bih1, const float* __restrict__ bhh1,
    const float* __restrict__ z, float* __restrict__ b0, float* __restrict__ b1,
    __hip_bfloat16* __restrict__ h0buf, __hip_bfloat16* __restrict__ h1buf) {
  for (int i = blockIdx.x * blockDim.x + threadIdx.x; i < 73728;
       i += blockDim.x * gridDim.x) {
    if (i < 4096) {
      int u = i >> 2, g = i & 3;
      b0[i] = bih0[g * 1024 + u] + bhh0[g * 1024 + u];
    } else if (i < 8192) {
      int r = i - 4096;
      int u = r >> 2, g = r & 3;
      b1[r] = bih1[g * 1024 + u] + bhh1[g * 1024 + u];
    } else {
      int j = i - 8192;  // 0..65535
      float zv = z[j];
      vstore_bf16(h0buf + j, zv);                       // h0 slot 0
      vstore_bf16(h1buf + 2 * 65536 + j, zv);           // h1 slot 2
    }
  }
}

// ------------- grid barrier: relaxed atomics + acquire-only inv -------------

__device__ __forceinline__ void bar_arrive(unsigned* __restrict__ root,
                                           unsigned* __restrict__ lvl,
                                           int phase, int tid) {
  __builtin_amdgcn_s_waitcnt(0);   // drain write-through h stores
  __syncthreads();                 // order all waves' stores before signal
  if (tid == 0) {
    unsigned old = __hip_atomic_fetch_add(lvl, 1u, __ATOMIC_RELAXED,
                                          __HIP_MEMORY_SCOPE_AGENT);
    if (old == (unsigned)phase * 32u + 31u)  // last of 32 in this group
      __hip_atomic_fetch_add(root, 1u, __ATOMIC_RELAXED,
                             __HIP_MEMORY_SCOPE_AGENT);
  }
}

__device__ __forceinline__ void bar_wait(unsigned* __restrict__ root, int phase,
                                         int tid) {
  if (tid == 0) {
    const unsigned tgt = (unsigned)(phase + 1) * 8u;
    while (__hip_atomic_load(root, __ATOMIC_RELAXED,
                             __HIP_MEMORY_SCOPE_AGENT) < tgt)
      __builtin_amdgcn_s_sleep(1);   // short sleep: tight inv clustering
    // acquire: s_waitcnt + buffer_inv (L1+XCD-L2 invalidate, NO writeback).
    // All 256 blocks reach this within ~poll-skew of each other, so L2
    // fills made AFTER this point survive the whole barrier interval.
    __builtin_amdgcn_fence(__ATOMIC_ACQUIRE, "agent");
  }
  __syncthreads();
}

// ---------------- projection helper (blocks 0..15) ----------------
// out[:, t_out, :] cols [pb*16, pb*16+16) = h1p @ Wlin^T + blin

__device__ __forceinline__ void do_proj(const __hip_bfloat16* __restrict__ h1p,
                                        const bf16x8* wp, float (*red)[16][68],
                                        const float* __restrict__ blin,
                                        float* __restrict__ out, int pb,
                                        int t_out, int tid, int w, int col,
                                        int kq) {
  f32x4 a0 = {0.f, 0.f, 0.f, 0.f}, a1 = a0, a2 = a0, a3 = a0;
  const __hip_bfloat16* ab = h1p + (w << 7) + (kq << 3);
#pragma unroll
  for (int c = 0; c < 4; ++c) {
    const __hip_bfloat16* p = ab + (c << 5);
    bf16x8 f0 = *(const bf16x8*)(p + ((size_t)col << 10));
    bf16x8 f1 = *(const bf16x8*)(p + ((size_t)(16 + col) << 10));
    bf16x8 f2 = *(const bf16x8*)(p + ((size_t)(32 + col) << 10));
    bf16x8 f3 = *(const bf16x8*)(p + ((size_t)(48 + col) << 10));
    a0 = __builtin_amdgcn_mfma_f32_16x16x32_bf16(f0, wp[c], a0, 0, 0, 0);
    a1 = __builtin_amdgcn_mfma_f32_16x16x32_bf16(f1, wp[c], a1, 0, 0, 0);
    a2 = __builtin_amdgcn_mfma_f32_16x16x32_bf16(f2, wp[c], a2, 0, 0, 0);
    a3 = __builtin_amdgcn_mfma_f32_16x16x32_bf16(f3, wp[c], a3, 0, 0, 0);
  }
  *(f32x4*)&red[w][col][(kq << 2)] = a0;
  *(f32x4*)&red[w][col][16 + (kq << 2)] = a1;
  *(f32x4*)&red[w][col][32 + (kq << 2)] = a2;
  *(f32x4*)&red[w][col][48 + (kq << 2)] = a3;
  __syncthreads();
#pragma unroll
  for (int i = 0; i < 2; ++i) {
    int idx = tid + (i << 9);
    int o_l = idx & 15, b = idx >> 4;
    float v = blin[(pb << 4) + o_l];
#pragma unroll
    for (int ww = 0; ww < 8; ++ww) v += red[ww][o_l][b];
    out[(((size_t)b << 9) + (size_t)t_out) * 256 + (pb << 4) + o_l] = v;
  }
  __syncthreads();  // red reused right after (phase B)
}

// ---------------- persistent kernel ----------------

__global__ __launch_bounds__(512) void k_persist(
    const __hip_bfloat16* __restrict__ xbf, const __hip_bfloat16* __restrict__ W0,
    const __hip_bfloat16* __restrict__ W1, const float* __restrict__ b0,
    const float* __restrict__ b1, const float* __restrict__ blin,
    __hip_bfloat16* __restrict__ h0buf, __hip_bfloat16* __restrict__ h1buf,
    float* __restrict__ out, unsigned* __restrict__ bar) {
  const int tid = threadIdx.x;
  const int lane = tid & 63;
  const int w = tid >> 6;          // wave id = K-split index (0..7)
  const int bid = blockIdx.x;
  const int cb = bid << 4;         // 16 gate-columns owned by this block
  const int col = lane & 15;
  const int kq = lane >> 4;
  const int n = cb + col;
  const bool isproj = (bid < 16);

  // ---- weights -> registers (persist across all 512 steps) ----
  bf16x8 wa[5], wb[8], wp[4];
  {
    const __hip_bfloat16* p = W0 + (size_t)n * 1280 + w * 160 + (kq << 3);
#pragma unroll
    for (int c = 0; c < 5; ++c) wa[c] = *(const bf16x8*)(p + (c << 5));
  }
  {
    const __hip_bfloat16* p = W1 + ((size_t)n << 11) + (w << 8) + (kq << 3);
#pragma unroll
    for (int c = 0; c < 8; ++c) wb[c] = *(const bf16x8*)(p + (c << 5));
  }
  if (isproj) {
    const __hip_bfloat16* p =
        W1 + ((size_t)(4096 + cb + col) << 11) + 1024 + (w << 7) + (kq << 3);
#pragma unroll
    for (int c = 0; c < 4; ++c) wp[c] = *(const bf16x8*)(p + (c << 5));
  } else {
#pragma unroll
    for (int c = 0; c < 4; ++c) wp[c] = bf16x8{0, 0, 0, 0, 0, 0, 0, 0};
  }

  // cell threads: tid<256 own (unit u_l of 4, batch bq); c-state in registers
  const int u_l = tid & 3, bq = tid >> 2;
  float bias0[4], bias1[4];
  if (tid < 256) {
#pragma unroll
    for (int g = 0; g < 4; ++g) {
      bias0[g] = b0[cb + (u_l << 2) + g];
      bias1[g] = b1[cb + (u_l << 2) + g];
    }
  }
  float c0v = 0.f, c1v = 0.f;

  __shared__ float red[8][16][68];  // K-partials; 68 keeps b128 16B-aligned

  unsigned* lvl = bar + 16 + ((bid & 7) << 6);  // 8 spread lvl-1 counters

  for (int t = 0; t < 512; ++t) {
    const __hip_bfloat16* h0prev = h0buf + ((size_t)(t & 1) << 16);
    const __hip_bfloat16* h0cur = h0buf + ((size_t)((t + 1) & 1) << 16);
    const __hip_bfloat16* h1prev = h1buf + ((size_t)((t + 2) % 3) << 16);
    const __hip_bfloat16* h1proj = h1buf + ((size_t)((t + 1) % 3) << 16);

    // ======== phase A: gates0 = [x_t | h0prev] @ W0cat^T ========
    // h0prev lines are L1/L2-resident: B_{t-1} read them in this same
    // barrier interval (no inv since).
    {
      f32x4 a0 = {0.f, 0.f, 0.f, 0.f}, a1 = a0, a2 = a0, a3 = a0;
#pragma unroll
      for (int c = 0; c < 5; ++c) {
        const int k0 = w * 160 + (c << 5);
        const __hip_bfloat16* ab;
        size_t rs;
        if (k0 < 256) {  // x part
          ab = xbf + ((size_t)t << 14) + k0 + (kq << 3);
          rs = 256;
        } else {         // h part
          ab = h0prev + (k0 - 256) + (kq << 3);
          rs = 1024;
        }
        bf16x8 f0 = *(const bf16x8*)(ab + (size_t)col * rs);
        bf16x8 f1 = *(const bf16x8*)(ab + (size_t)(16 + col) * rs);
        bf16x8 f2 = *(const bf16x8*)(ab + (size_t)(32 + col) * rs);
        bf16x8 f3 = *(const bf16x8*)(ab + (size_t)(48 + col) * rs);
        a0 = __builtin_amdgcn_mfma_f32_16x16x32_bf16(f0, wa[c], a0, 0, 0, 0);
        a1 = __builtin_amdgcn_mfma_f32_16x16x32_bf16(f1, wa[c], a1, 0, 0, 0);
        a2 = __builtin_amdgcn_mfma_f32_16x16x32_bf16(f2, wa[c], a2, 0, 0, 0);
        a3 = __builtin_amdgcn_mfma_f32_16x16x32_bf16(f3, wa[c], a3, 0, 0, 0);
      }
      *(f32x4*)&red[w][col][(kq << 2)] = a0;
      *(f32x4*)&red[w][col][16 + (kq << 2)] = a1;
      *(f32x4*)&red[w][col][32 + (kq << 2)] = a2;
      *(f32x4*)&red[w][col][48 + (kq << 2)] = a3;
    }
    __syncthreads();
    if (tid < 256) {  // 8-way K-reduce + LSTM cell 0
      float gg[4];
#pragma unroll
      for (int g = 0; g < 4; ++g) {
        float v = bias0[g];
#pragma unroll
        for (int ww = 0; ww < 8; ++ww) v += red[ww][(u_l << 2) + g][bq];
        gg[g] = v;
      }
      float cn = sigm(gg[1]) * c0v + sigm(gg[0]) * tanhf(gg[2]);
      c0v = cn;
      float hn = sigm(gg[3]) * tanhf(cn);
      vstore_bf16(h0buf + ((size_t)((t + 1) & 1) << 16) + ((size_t)bq << 10) +
                      (cb >> 2) + u_l,
                  hn);
    }

    // ---- single barrier: publishes h0[t] (phase A) and h1[t-1] (B_{t-1}) --
    bar_arrive(bar, lvl, t, tid);
    bar_wait(bar, t, tid);        // all 256 invs fire here, clustered
    // proj h1[t-2] -> out[t-2] AFTER the inv (R4 ran it before bar_wait,
    // delaying these 16 blocks' invs by ~us and wiping other blocks' fresh
    // L2 fills -> whole broadcast fell to the LLC).
    if (isproj && t >= 2)
      do_proj(h1proj, wp, red, blin, out, bid, t - 2, tid, w, col, kq);

    // ======== phase B: gates1 = [h0cur | h1prev] @ W1^T ========
    {
      const __hip_bfloat16* ab =
          ((w < 4) ? h0cur : h1prev) + ((w & 3) << 8) + (kq << 3);
      f32x4 a0 = {0.f, 0.f, 0.f, 0.f}, a1 = a0, a2 = a0, a3 = a0;
#pragma unroll
      for (int c = 0; c < 8; ++c) {
        const __hip_bfloat16* p = ab + (c << 5);
        bf16x8 f0 = *(const bf16x8*)(p + ((size_t)col << 10));
        bf16x8 f1 = *(const bf16x8*)(p + ((size_t)(16 + col) << 10));
        bf16x8 f2 = *(const bf16x8*)(p + ((size_t)(32 + col) << 10));
        bf16x8 f3 = *(const bf16x8*)(p + ((size_t)(48 + col) << 10));
        a0 = __builtin_amdgcn_mfma_f32_16x16x32_bf16(f0, wb[c], a0, 0, 0, 0);
        a1 = __builtin_amdgcn_mfma_f32_16x16x32_bf16(f1, wb[c], a1, 0, 0, 0);
        a2 = __builtin_amdgcn_mfma_f32_16x16x32_bf16(f2, wb[c], a2, 0, 0, 0);
        a3 = __builtin_amdgcn_mfma_f32_16x16x32_bf16(f3, wb[c], a3, 0, 0, 0);
      }
      *(f32x4*)&red[w][col][(kq << 2)] = a0;
      *(f32x4*)&red[w][col][16 + (kq << 2)] = a1;
      *(f32x4*)&red[w][col][32 + (kq << 2)] = a2;
      *(f32x4*)&red[w][col][48 + (kq << 2)] = a3;
    }
    __syncthreads();
    if (tid < 256) {  // 8-way K-reduce + LSTM cell 1
      float gg[4];
#pragma unroll
      for (int g = 0; g < 4; ++g) {
        float v = bias1[g];
#pragma unroll
        for (int ww = 0; ww < 8; ++ww) v += red[ww][(u_l << 2) + g][bq];
        gg[g] = v;
      }
      float cn = sigm(gg[1]) * c1v + sigm(gg[0]) * tanhf(gg[2]);
      c1v = cn;
      float hn = sigm(gg[3]) * tanhf(cn);
      vstore_bf16(h1buf + ((size_t)(t % 3) << 16) + ((size_t)bq << 10) +
                      (cb >> 2) + u_l,
                  hn);
    }
    __syncthreads();  // red safe for next iteration's phase A
  }

  // final barrier publishes h1[511]; project tail out[510], out[511]
  bar_arrive(bar, lvl, 512, tid);
  bar_wait(bar, 512, tid);
  if (isproj) {
    do_proj(h1buf + ((size_t)(510 % 3) << 16), wp, red, blin, out, bid, 510,
            tid, w, col, kq);
    do_proj(h1buf + ((size_t)(511 % 3) << 16), wp, red, blin, out, bid, 511,
            tid, w, col, kq);
  }
}

// ---------------- host launch ----------------

extern "C" void kernel_launch(void* const* d_in, const int* in_sizes, int n_in,
                              void* d_out, int out_size, void* d_ws, size_t ws_size,
                              hipStream_t stream) {
  const float* z = (const float*)d_in[0];
  const float* x = (const float*)d_in[1];
  const float* Wih0 = (const float*)d_in[2];
  const float* Whh0 = (const float*)d_in[3];
  const float* bih0 = (const float*)d_in[4];
  const float* bhh0 = (const float*)d_in[5];
  const float* Wih1 = (const float*)d_in[6];
  const float* Whh1 = (const float*)d_in[7];
  const float* bih1 = (const float*)d_in[8];
  const float* bhh1 = (const float*)d_in[9];
  const float* Wlin = (const float*)d_in[10];
  const float* blin = (const float*)d_in[11];
  float* out = (float*)d_out;

  char* ws = (char*)d_ws;
  __hip_bfloat16* W0 = (__hip_bfloat16*)(ws);                // 10,485,760 B
  __hip_bfloat16* W1 = (__hip_bfloat16*)(ws + 10485760);     // 17,825,792 B
  __hip_bfloat16* xbf = (__hip_bfloat16*)(ws + 28311552);    // 16,777,216 B
  float* b0 = (float*)(ws + 45088768);                       // 16,384 B
  float* b1 = (float*)(ws + 45105152);                       // 16,384 B
  __hip_bfloat16* h0buf = (__hip_bfloat16*)(ws + 45121536);  // 262,144 B (2 slots)
  __hip_bfloat16* h1buf = (__hip_bfloat16*)(ws + 45383680);  // 393,216 B (3 slots)
  unsigned* bar = (unsigned*)(ws + 45776896);                // 4,096 B

  hipMemsetAsync(bar, 0, 4096, stream);  // ws is re-poisoned every call
  prep_w0<<<4096, 256, 0, stream>>>(Wih0, Whh0, W0);
  prep_w1<<<4096, 256, 0, stream>>>(Wih1, Whh1, Wlin, W1);
  prep_x<<<4096, 256, 0, stream>>>(x, xbf);
  prep_misc<<<288, 256, 0, stream>>>(bih0, bhh0, bih1, bhh1, z, b0, b1, h0buf,
                                     h1buf);

  k_persist<<<256, 512, 0, stream>>>(xbf, W0, W1, b0, b1, blin, h0buf, h1buf,
                                     out, bar);
}

// Round 6
// 10676.559 us; speedup vs baseline: 1.0376x; 1.0376x over previous
//
#include <hip/hip_runtime.h>
#include <hip/hip_bf16.h>
#include <math.h>

// LSTM decoder: B=64, T=512, IN=256, OUT=256, H=1024, 2 layers + linear head.
// Round 6: persistent kernel (256 blocks x 512 threads), weights in VGPRs,
// cell state in registers, cached h loads + clustered acquire-inv, single
// barrier/step. Changes vs R5 (attacking LLC hot-spot congestion):
//  - Barrier de-congestion: root / 8 group counters / 16 broadcast epoch
//    flags each on a PRIVATE 128B LLC line (R5 had root + group0 + polls all
//    on ONE line; 256 pollers @ ~700cyc round-trip oversubscribed the bank
//    ~13x -> ~10+us queueing per barrier = the R3/R4/R5 invariant).
//    Pollers now poll flags[bid&15] (<=16 pollers/line); finisher writes 16.
//  - Packed h stores: cell -> LDS -> wave0 packs 4xbf16 -> ONE
//    global_store_dwordx2 (sc0 sc1) per lane; kills the 2B-scattered
//    write-through partial-line amplification (WRITE_SIZE 561MB for 128MB
//    of h) and makes the pre-arrive drain a single ack.
//  - Fast clamped __expf-based sigmoid/tanh in the cell epilogue.

typedef __attribute__((ext_vector_type(8))) short bf16x8;   // 8 x bf16
typedef __attribute__((ext_vector_type(4))) float f32x4;

__device__ __forceinline__ float sigm(float v) {
  return 1.f / (1.f + __expf(-v));
}
__device__ __forceinline__ float tanh_f(float x) {
  float xc = fminf(fmaxf(x, -15.f), 15.f);
  float e = __expf(2.f * xc);
  return (e - 1.f) / (e + 1.f);
}

// write-through (sc0 sc1) 2B store (prep only)
__device__ __forceinline__ void vstore_bf16(__hip_bfloat16* p, float v) {
  __hip_bfloat16 hb = __float2bfloat16(v);
  unsigned short us;
  __builtin_memcpy(&us, &hb, 2);
  *(volatile unsigned short*)p = us;
}

// ---------------- prep kernels (one-time per launch) ----------------

// W0cat[u*4+g][k] : k<256 -> Wih0[g*1024+u][k], else Whh0[g*1024+u][k-256]
__global__ __launch_bounds__(256) void prep_w0(const float* __restrict__ Wih0,
                                               const float* __restrict__ Whh0,
                                               __hip_bfloat16* __restrict__ W0) {
  const unsigned n = 4096u * 1280u;
  for (unsigned d = blockIdx.x * blockDim.x + threadIdx.x; d < n;
       d += blockDim.x * gridDim.x) {
    unsigned r = d / 1280u;
    unsigned k = d - r * 1280u;
    unsigned u = r >> 2, g = r & 3u;
    unsigned srow = g * 1024u + u;
    float v = (k < 256u) ? Wih0[(size_t)srow * 256u + k]
                         : Whh0[(size_t)srow * 1024u + (k - 256u)];
    W0[d] = __float2bfloat16(v);
  }
}

// W1ext[4352][2048]: rows<4096 reordered LSTM1 weights [Wih1|Whh1];
// rows 4096+o: [zeros(1024) | Wlin[o]]
__global__ __launch_bounds__(256) void prep_w1(const float* __restrict__ Wih1,
                                               const float* __restrict__ Whh1,
                                               const float* __restrict__ Wlin,
                                               __hip_bfloat16* __restrict__ W1) {
  const unsigned n = 4352u * 2048u;
  for (unsigned d = blockIdx.x * blockDim.x + threadIdx.x; d < n;
       d += blockDim.x * gridDim.x) {
    unsigned r = d >> 11;
    unsigned k = d & 2047u;
    float v;
    if (r < 4096u) {
      unsigned u = r >> 2, g = r & 3u;
      unsigned srow = g * 1024u + u;
      v = (k < 1024u) ? Wih1[(size_t)srow * 1024u + k]
                      : Whh1[(size_t)srow * 1024u + (k - 1024u)];
    } else {
      unsigned o = r - 4096u;
      v = (k < 1024u) ? 0.f : Wlin[(size_t)o * 1024u + (k - 1024u)];
    }
    W1[d] = __float2bfloat16(v);
  }
}

// xbf[t][b][k] = bf16( t==0 ? 0 : x[b][t-1][k] )   (teacher forcing shift)
__global__ __launch_bounds__(256) void prep_x(const float* __restrict__ x,
                                              __hip_bfloat16* __restrict__ xbf) {
  const unsigned n = 512u * 64u * 256u;
  for (unsigned d = blockIdx.x * blockDim.x + threadIdx.x; d < n;
       d += blockDim.x * gridDim.x) {
    unsigned t = d >> 14;
    unsigned b = (d >> 8) & 63u;
    unsigned k = d & 255u;
    float v = (t == 0u) ? 0.f : x[((size_t)b * 512u + (t - 1u)) * 256u + k];
    xbf[d] = __float2bfloat16(v);
  }
}

// biases + h init: h0[-1] -> slot 0, h1[-1] -> slot 2 (triple-buffered)
__global__ __launch_bounds__(256) void prep_misc(
    const float* __restrict__ bih0, const float* __restrict__ bhh0,
    const float* __restrict__ bih1, const float* __restrict__ bhh1,
    const float* __restrict__ z, float* __restrict__ b0, float* __restrict__ b1,
    __hip_bfloat16* __restrict__ h0buf, __hip_bfloat16* __restrict__ h1buf) {
  for (int i = blockIdx.x * blockDim.x + threadIdx.x; i < 73728;
       i += blockDim.x * gridDim.x) {
    if (i < 4096) {
      int u = i >> 2, g = i & 3;
      b0[i] = bih0[g * 1024 + u] + bhh0[g * 1024 + u];
    } else if (i < 8192) {
      int r = i - 4096;
      int u = r >> 2, g = r & 3;
      b1[r] = bih1[g * 1024 + u] + bhh1[g * 1024 + u];
    } else {
      int j = i - 8192;  // 0..65535
      float zv = z[j];
      vstore_bf16(h0buf + j, zv);              // h0 slot 0
      vstore_bf16(h1buf + 2 * 65536 + j, zv);  // h1 slot 2
    }
  }
}

// ---- grid barrier: spread lines, 16-flag broadcast, relaxed atomics ----
// layout (uint index): root=bar[0]; lvl[g]=bar[32*(1+g)] g<8;
// flags[i]=bar[32*(9+i)] i<16. Each on its own 128B line.

__device__ __forceinline__ void bar_arrive(unsigned* __restrict__ bar,
                                           int phase, int tid, int bid) {
  __builtin_amdgcn_s_waitcnt(0);   // drain this wave's h store (wave 0)
  __syncthreads();                 // order all waves before signal
  if (tid == 0) {
    unsigned old = __hip_atomic_fetch_add(&bar[32 * (1 + (bid & 7))], 1u,
                                          __ATOMIC_RELAXED,
                                          __HIP_MEMORY_SCOPE_AGENT);
    if (old == (unsigned)phase * 32u + 31u) {        // group finisher
      unsigned r = __hip_atomic_fetch_add(&bar[0], 1u, __ATOMIC_RELAXED,
                                          __HIP_MEMORY_SCOPE_AGENT);
      if (r == (unsigned)phase * 8u + 7u) {          // grid finisher
#pragma unroll
        for (int i = 0; i < 16; ++i)
          __hip_atomic_store(&bar[32 * (9 + i)], (unsigned)(phase + 1),
                             __ATOMIC_RELAXED, __HIP_MEMORY_SCOPE_AGENT);
      }
    }
  }
}

__device__ __forceinline__ void bar_wait(unsigned* __restrict__ bar, int phase,
                                         int tid, int bid) {
  if (tid == 0) {
    unsigned* f = &bar[32 * (9 + (bid & 15))];
    while (__hip_atomic_load(f, __ATOMIC_RELAXED, __HIP_MEMORY_SCOPE_AGENT) <
           (unsigned)(phase + 1))
      __builtin_amdgcn_s_sleep(4);
    // acquire: buffer_inv (L1+XCD-L2 invalidate, no writeback), clustered
    __builtin_amdgcn_fence(__ATOMIC_ACQUIRE, "agent");
  }
  __syncthreads();
}

// ---------------- projection helper (blocks 0..15) ----------------

__device__ __forceinline__ void do_proj(const __hip_bfloat16* __restrict__ h1p,
                                        const bf16x8* wp, float (*red)[16][68],
                                        const float* __restrict__ blin,
                                        float* __restrict__ out, int pb,
                                        int t_out, int tid, int w, int col,
                                        int kq) {
  f32x4 a0 = {0.f, 0.f, 0.f, 0.f}, a1 = a0, a2 = a0, a3 = a0;
  const __hip_bfloat16* ab = h1p + (w << 7) + (kq << 3);
#pragma unroll
  for (int c = 0; c < 4; ++c) {
    const __hip_bfloat16* p = ab + (c << 5);
    bf16x8 f0 = *(const bf16x8*)(p + ((size_t)col << 10));
    bf16x8 f1 = *(const bf16x8*)(p + ((size_t)(16 + col) << 10));
    bf16x8 f2 = *(const bf16x8*)(p + ((size_t)(32 + col) << 10));
    bf16x8 f3 = *(const bf16x8*)(p + ((size_t)(48 + col) << 10));
    a0 = __builtin_amdgcn_mfma_f32_16x16x32_bf16(f0, wp[c], a0, 0, 0, 0);
    a1 = __builtin_amdgcn_mfma_f32_16x16x32_bf16(f1, wp[c], a1, 0, 0, 0);
    a2 = __builtin_amdgcn_mfma_f32_16x16x32_bf16(f2, wp[c], a2, 0, 0, 0);
    a3 = __builtin_amdgcn_mfma_f32_16x16x32_bf16(f3, wp[c], a3, 0, 0, 0);
  }
  *(f32x4*)&red[w][col][(kq << 2)] = a0;
  *(f32x4*)&red[w][col][16 + (kq << 2)] = a1;
  *(f32x4*)&red[w][col][32 + (kq << 2)] = a2;
  *(f32x4*)&red[w][col][48 + (kq << 2)] = a3;
  __syncthreads();
#pragma unroll
  for (int i = 0; i < 2; ++i) {
    int idx = tid + (i << 9);
    int o_l = idx & 15, b = idx >> 4;
    float v = blin[(pb << 4) + o_l];
#pragma unroll
    for (int ww = 0; ww < 8; ++ww) v += red[ww][o_l][b];
    out[(((size_t)b << 9) + (size_t)t_out) * 256 + (pb << 4) + o_l] = v;
  }
  __syncthreads();  // red reused right after (phase B)
}

// ---------------- persistent kernel ----------------

__global__ __launch_bounds__(512) void k_persist(
    const __hip_bfloat16* __restrict__ xbf, const __hip_bfloat16* __restrict__ W0,
    const __hip_bfloat16* __restrict__ W1, const float* __restrict__ b0,
    const float* __restrict__ b1, const float* __restrict__ blin,
    __hip_bfloat16* __restrict__ h0buf, __hip_bfloat16* __restrict__ h1buf,
    float* __restrict__ out, unsigned* __restrict__ bar) {
  const int tid = threadIdx.x;
  const int lane = tid & 63;
  const int w = tid >> 6;          // wave id = K-split index (0..7)
  const int bid = blockIdx.x;
  const int cb = bid << 4;         // 16 gate-columns owned by this block
  const int col = lane & 15;
  const int kq = lane >> 4;
  const int n = cb + col;
  const bool isproj = (bid < 16);

  // ---- weights -> registers (persist across all 512 steps) ----
  bf16x8 wa[5], wb[8], wp[4];
  {
    const __hip_bfloat16* p = W0 + (size_t)n * 1280 + w * 160 + (kq << 3);
#pragma unroll
    for (int c = 0; c < 5; ++c) wa[c] = *(const bf16x8*)(p + (c << 5));
  }
  {
    const __hip_bfloat16* p = W1 + ((size_t)n << 11) + (w << 8) + (kq << 3);
#pragma unroll
    for (int c = 0; c < 8; ++c) wb[c] = *(const bf16x8*)(p + (c << 5));
  }
  if (isproj) {
    const __hip_bfloat16* p =
        W1 + ((size_t)(4096 + cb + col) << 11) + 1024 + (w << 7) + (kq << 3);
#pragma unroll
    for (int c = 0; c < 4; ++c) wp[c] = *(const bf16x8*)(p + (c << 5));
  } else {
#pragma unroll
    for (int c = 0; c < 4; ++c) wp[c] = bf16x8{0, 0, 0, 0, 0, 0, 0, 0};
  }

  // cell threads: tid<256 own (unit u_l of 4, batch bq); c-state in registers
  const int u_l = tid & 3, bq = tid >> 2;
  float bias0[4], bias1[4];
  if (tid < 256) {
#pragma unroll
    for (int g = 0; g < 4; ++g) {
      bias0[g] = b0[cb + (u_l << 2) + g];
      bias1[g] = b1[cb + (u_l << 2) + g];
    }
  }
  float c0v = 0.f, c1v = 0.f;

  __shared__ float red[8][16][68];  // K-partials
  __shared__ __align__(8) __hip_bfloat16 hsh[64][4];  // h pack staging

  for (int t = 0; t < 512; ++t) {
    const __hip_bfloat16* h0prev = h0buf + ((size_t)(t & 1) << 16);
    const __hip_bfloat16* h0cur = h0buf + ((size_t)((t + 1) & 1) << 16);
    const __hip_bfloat16* h1prev = h1buf + ((size_t)((t + 2) % 3) << 16);
    const __hip_bfloat16* h1proj = h1buf + ((size_t)((t + 1) % 3) << 16);

    // ======== phase A: gates0 = [x_t | h0prev] @ W0cat^T ========
    {
      f32x4 a0 = {0.f, 0.f, 0.f, 0.f}, a1 = a0, a2 = a0, a3 = a0;
#pragma unroll
      for (int c = 0; c < 5; ++c) {
        const int k0 = w * 160 + (c << 5);
        const __hip_bfloat16* ab;
        size_t rs;
        if (k0 < 256) {  // x part
          ab = xbf + ((size_t)t << 14) + k0 + (kq << 3);
          rs = 256;
        } else {         // h part
          ab = h0prev + (k0 - 256) + (kq << 3);
          rs = 1024;
        }
        bf16x8 f0 = *(const bf16x8*)(ab + (size_t)col * rs);
        bf16x8 f1 = *(const bf16x8*)(ab + (size_t)(16 + col) * rs);
        bf16x8 f2 = *(const bf16x8*)(ab + (size_t)(32 + col) * rs);
        bf16x8 f3 = *(const bf16x8*)(ab + (size_t)(48 + col) * rs);
        a0 = __builtin_amdgcn_mfma_f32_16x16x32_bf16(f0, wa[c], a0, 0, 0, 0);
        a1 = __builtin_amdgcn_mfma_f32_16x16x32_bf16(f1, wa[c], a1, 0, 0, 0);
        a2 = __builtin_amdgcn_mfma_f32_16x16x32_bf16(f2, wa[c], a2, 0, 0, 0);
        a3 = __builtin_amdgcn_mfma_f32_16x16x32_bf16(f3, wa[c], a3, 0, 0, 0);
      }
      *(f32x4*)&red[w][col][(kq << 2)] = a0;
      *(f32x4*)&red[w][col][16 + (kq << 2)] = a1;
      *(f32x4*)&red[w][col][32 + (kq << 2)] = a2;
      *(f32x4*)&red[w][col][48 + (kq << 2)] = a3;
    }
    __syncthreads();
    if (tid < 256) {  // 8-way K-reduce + LSTM cell 0 -> LDS
      float gg[4];
#pragma unroll
      for (int g = 0; g < 4; ++g) {
        float v = bias0[g];
#pragma unroll
        for (int ww = 0; ww < 8; ++ww) v += red[ww][(u_l << 2) + g][bq];
        gg[g] = v;
      }
      float cn = sigm(gg[1]) * c0v + sigm(gg[0]) * tanh_f(gg[2]);
      c0v = cn;
      hsh[bq][u_l] = __float2bfloat16(sigm(gg[3]) * tanh_f(cn));
    }
    __syncthreads();
    if (w == 0) {  // wave 0: pack 4 bf16 -> one 8B write-through store
      unsigned long long pk = *(const unsigned long long*)&hsh[lane][0];
      *(volatile unsigned long long*)(h0buf + ((size_t)((t + 1) & 1) << 16) +
                                      ((size_t)lane << 10) + (bid << 2)) = pk;
    }

    // ---- single barrier: publishes h0[t] (phase A) and h1[t-1] (B_{t-1}) --
    bar_arrive(bar, t, tid, bid);
    bar_wait(bar, t, tid, bid);
    if (isproj && t >= 2)
      do_proj(h1proj, wp, red, blin, out, bid, t - 2, tid, w, col, kq);

    // ======== phase B: gates1 = [h0cur | h1prev] @ W1^T ========
    {
      const __hip_bfloat16* ab =
          ((w < 4) ? h0cur : h1prev) + ((w & 3) << 8) + (kq << 3);
      f32x4 a0 = {0.f, 0.f, 0.f, 0.f}, a1 = a0, a2 = a0, a3 = a0;
#pragma unroll
      for (int c = 0; c < 8; ++c) {
        const __hip_bfloat16* p = ab + (c << 5);
        bf16x8 f0 = *(const bf16x8*)(p + ((size_t)col << 10));
        bf16x8 f1 = *(const bf16x8*)(p + ((size_t)(16 + col) << 10));
        bf16x8 f2 = *(const bf16x8*)(p + ((size_t)(32 + col) << 10));
        bf16x8 f3 = *(const bf16x8*)(p + ((size_t)(48 + col) << 10));
        a0 = __builtin_amdgcn_mfma_f32_16x16x32_bf16(f0, wb[c], a0, 0, 0, 0);
        a1 = __builtin_amdgcn_mfma_f32_16x16x32_bf16(f1, wb[c], a1, 0, 0, 0);
        a2 = __builtin_amdgcn_mfma_f32_16x16x32_bf16(f2, wb[c], a2, 0, 0, 0);
        a3 = __builtin_amdgcn_mfma_f32_16x16x32_bf16(f3, wb[c], a3, 0, 0, 0);
      }
      *(f32x4*)&red[w][col][(kq << 2)] = a0;
      *(f32x4*)&red[w][col][16 + (kq << 2)] = a1;
      *(f32x4*)&red[w][col][32 + (kq << 2)] = a2;
      *(f32x4*)&red[w][col][48 + (kq << 2)] = a3;
    }
    __syncthreads();
    if (tid < 256) {  // 8-way K-reduce + LSTM cell 1 -> LDS
      float gg[4];
#pragma unroll
      for (int g = 0; g < 4; ++g) {
        float v = bias1[g];
#pragma unroll
        for (int ww = 0; ww < 8; ++ww) v += red[ww][(u_l << 2) + g][bq];
        gg[g] = v;
      }
      float cn = sigm(gg[1]) * c1v + sigm(gg[0]) * tanh_f(gg[2]);
      c1v = cn;
      hsh[bq][u_l] = __float2bfloat16(sigm(gg[3]) * tanh_f(cn));
    }
    __syncthreads();
    if (w == 0) {  // wave 0: pack + store h1[t]
      unsigned long long pk = *(const unsigned long long*)&hsh[lane][0];
      *(volatile unsigned long long*)(h1buf + ((size_t)(t % 3) << 16) +
                                      ((size_t)lane << 10) + (bid << 2)) = pk;
    }
    __syncthreads();  // hsh/red safe for next iteration
  }

  // final barrier publishes h1[511]; project tail out[510], out[511]
  bar_arrive(bar, 512, tid, bid);
  bar_wait(bar, 512, tid, bid);
  if (isproj) {
    do_proj(h1buf + ((size_t)(510 % 3) << 16), wp, red, blin, out, bid, 510,
            tid, w, col, kq);
    do_proj(h1buf + ((size_t)(511 % 3) << 16), wp, red, blin, out, bid, 511,
            tid, w, col, kq);
  }
}

// ---------------- host launch ----------------

extern "C" void kernel_launch(void* const* d_in, const int* in_sizes, int n_in,
                              void* d_out, int out_size, void* d_ws, size_t ws_size,
                              hipStream_t stream) {
  const float* z = (const float*)d_in[0];
  const float* x = (const float*)d_in[1];
  const float* Wih0 = (const float*)d_in[2];
  const float* Whh0 = (const float*)d_in[3];
  const float* bih0 = (const float*)d_in[4];
  const float* bhh0 = (const float*)d_in[5];
  const float* Wih1 = (const float*)d_in[6];
  const float* Whh1 = (const float*)d_in[7];
  const float* bih1 = (const float*)d_in[8];
  const float* bhh1 = (const float*)d_in[9];
  const float* Wlin = (const float*)d_in[10];
  const float* blin = (const float*)d_in[11];
  float* out = (float*)d_out;

  char* ws = (char*)d_ws;
  __hip_bfloat16* W0 = (__hip_bfloat16*)(ws);                // 10,485,760 B
  __hip_bfloat16* W1 = (__hip_bfloat16*)(ws + 10485760);     // 17,825,792 B
  __hip_bfloat16* xbf = (__hip_bfloat16*)(ws + 28311552);    // 16,777,216 B
  float* b0 = (float*)(ws + 45088768);                       // 16,384 B
  float* b1 = (float*)(ws + 45105152);                       // 16,384 B
  __hip_bfloat16* h0buf = (__hip_bfloat16*)(ws + 45121536);  // 262,144 B (2 slots)
  __hip_bfloat16* h1buf = (__hip_bfloat16*)(ws + 45383680);  // 393,216 B (3 slots)
  unsigned* bar = (unsigned*)(ws + 45776896);                // 4,096 B

  hipMemsetAsync(bar, 0, 4096, stream);  // ws is re-poisoned every call
  prep_w0<<<4096, 256, 0, stream>>>(Wih0, Whh0, W0);
  prep_w1<<<4096, 256, 0, stream>>>(Wih1, Whh1, Wlin, W1);
  prep_x<<<4096, 256, 0, stream>>>(x, xbf);
  prep_misc<<<288, 256, 0, stream>>>(bih0, bhh0, bih1, bhh1, z, b0, b1, h0buf,
                                     h1buf);

  k_persist<<<256, 512, 0, stream>>>(xbf, W0, W1, b0, b1, blin, h0buf, h1buf,
                                     out, bar);
}